// Round 1
// baseline (263.181 us; speedup 1.0000x reference)
//
#include <hip/hip_runtime.h>

#define IH 126
#define IW 126
#define HW 15876      // 126*126
#define OH 124
#define OW 124
#define OHW 15376     // 124*124

// ---------------------------------------------------------------- conv_in
__global__ __launch_bounds__(256) void conv_in_kernel(
    const float* __restrict__ x, const float* __restrict__ w,
    const float* __restrict__ b, float* __restrict__ y)
{
  int pix = blockIdx.x * 256 + threadIdx.x;
  if (pix >= HW) return;
  int oc = blockIdx.y;                 // wave-uniform -> weights become s_loads
  int h  = pix / IW;
  int wc = pix - h * IW;
  const float* wp = w + oc * 27;
  float acc = b[oc];
#pragma unroll
  for (int ci = 0; ci < 3; ci++)
#pragma unroll
    for (int ky = 0; ky < 3; ky++)
#pragma unroll
      for (int kx = 0; kx < 3; kx++)
        acc = fmaf(x[ci * 128 * 128 + (h + ky) * 128 + (wc + kx)],
                   wp[ci * 9 + ky * 3 + kx], acc);
  y[oc * HW + pix] = acc;
}

// ---------------------------------------------------------------- involution v4
// Tile 8x4, 512 blocks (2/CU), 512 threads. ALL weight reads wave-uniform
// (s_load from scalar cache) — no per-thread vector global loads.
//   xs[pos][68] pos-major: phase D reads = uniform base + lane (conflict-free);
//   phase B reads b128 over channels.
//   v4: tss is its OWN buffer (no wvs-tail overlay) -> the mid-phase-C barrier
//   is gone. LDS 65,728 B <= 80 KB -> still 2 blocks/CU.
__global__ __launch_bounds__(512, 4) void inv_kernel(
    const float* __restrict__ x, float* __restrict__ y,
    const float* __restrict__ wr, const float* __restrict__ br,
    const float* __restrict__ gam, const float* __restrict__ bet,
    const float* __restrict__ mu, const float* __restrict__ var,
    const float* __restrict__ wspan, const float* __restrict__ bspan)
{
  __shared__ __align__(16) float xs[140][68];   // 38,080 B; aliased by ob[64][33] in E
  __shared__ __align__(16) float wvs[6272];     // 25,088 B; 196 pairs x 32 pixels
  __shared__ __align__(16) float tss[640];      // 2,560 B;  [32 pixels][20]
  float* ob  = &xs[0][0];                       // [64][33] alias

  int tid = threadIdx.x;
  int bx = blockIdx.x & 15, by = blockIdx.x >> 4;
  int ox0 = bx * 8, oy0 = by * 4;
  int xh0 = ox0 - 3, yh0 = oy0 - 3;

  // ---- Phase A: stage x halo (14 cols x 10 rows x 64 ch), zero-padded
  for (int idx = tid; idx < 140 * 64; idx += 512) {
    int c = idx / 140;
    int pos = idx - c * 140;
    int row = pos / 14;
    int col = pos - row * 14;
    int gy = yh0 + row, gx = xh0 + col;
    float v = 0.f;
    if (gy >= 0 && gy < IH && gx >= 0 && gx < IW)
      v = x[c * HW + gy * IW + gx];
    xs[pos][c] = v;
  }
  __syncthreads();

  int w_ = __builtin_amdgcn_readfirstlane(tid >> 6);  // wave 0..7
  int ln = tid & 63;
  int p  = ln & 31;                   // pixel 0..31 (upper 32 lanes duplicate)
  int prow = p >> 3, pcol = p & 7;
  int pc = (prow + 3) * 14 + (pcol + 3);

  // ---- Phase B: t = ReLU(BN(Wr.x)); wave w_ does cr = 2w_, 2w_+1 (uniform)
  {
    int cr0 = 2 * w_;
    const float* wa = wr + cr0 * 64;  // uniform -> s_load
    const float* wb = wa + 64;
    float a0 = 0.f, a1 = 0.f;
#pragma unroll
    for (int ci = 0; ci < 64; ci += 4) {
      float4 xv = *(const float4*)&xs[pc][ci];
      a0 = fmaf(xv.x, wa[ci + 0], a0); a1 = fmaf(xv.x, wb[ci + 0], a1);
      a0 = fmaf(xv.y, wa[ci + 1], a0); a1 = fmaf(xv.y, wb[ci + 1], a1);
      a0 = fmaf(xv.z, wa[ci + 2], a0); a1 = fmaf(xv.z, wb[ci + 2], a1);
      a0 = fmaf(xv.w, wa[ci + 3], a0); a1 = fmaf(xv.w, wb[ci + 3], a1);
    }
    float s0 = gam[cr0]     * rsqrtf(var[cr0]     + 1e-5f);
    float s1 = gam[cr0 + 1] * rsqrtf(var[cr0 + 1] + 1e-5f);
    float t0 = (a0 + br[cr0]     - mu[cr0])     * s0 + bet[cr0];
    float t1 = (a1 + br[cr0 + 1] - mu[cr0 + 1]) * s1 + bet[cr0 + 1];
    if (ln < 32) {
      tss[p * 20 + cr0]     = fmaxf(t0, 0.f);
      tss[p * 20 + cr0 + 1] = fmaxf(t1, 0.f);
    }
  }
  __syncthreads();

  // ---- Phase C: span. wave w_ owns uniform pairs (g*49+k) = w_ + 8j.
  //      (no mid-phase barrier: tss is no longer overlaid on wvs)
  {
    float tv[16];
#pragma unroll
    for (int i = 0; i < 4; i++) {
      float4 t4 = *(const float4*)&tss[p * 20 + 4 * i];
      tv[4 * i] = t4.x; tv[4 * i + 1] = t4.y;
      tv[4 * i + 2] = t4.z; tv[4 * i + 3] = t4.w;
    }
    for (int j = 0; j < 25; j++) {
      int pair = w_ + 8 * j;           // wave-uniform
      if (pair < 196) {
        const float* wk = wspan + pair * 16;   // uniform -> s_load_dwordx16
        float a = bspan[pair];
#pragma unroll
        for (int i = 0; i < 16; i++) a = fmaf(tv[i], wk[i], a);
        if (ln < 32) wvs[pair * 32 + pcol * 4 + prow] = a;
      }
    }
  }
  __syncthreads();

  // ---- Phase D: einsum. wave = output column w_, lane = channel.
  float acc0 = 0.f, acc1 = 0.f, acc2 = 0.f, acc3 = 0.f;
  {
    int c = ln;
    int g = ln >> 4;
    float xw[4][7];
#pragma unroll
    for (int r = 0; r < 4; r++)
#pragma unroll
      for (int kx = 0; kx < 7; kx++)
        xw[r][kx] = xs[r * 14 + w_ + kx][c];   // uniform base + lane: conflict-free
#pragma unroll
    for (int ky = 0; ky < 7; ky++) {
      if (ky > 0) {
#pragma unroll
        for (int r = 0; r < 3; r++)
#pragma unroll
          for (int kx = 0; kx < 7; kx++) xw[r][kx] = xw[r + 1][kx];
#pragma unroll
        for (int kx = 0; kx < 7; kx++)
          xw[3][kx] = xs[(ky + 3) * 14 + w_ + kx][c];
      }
#pragma unroll
      for (int kx = 0; kx < 7; kx++) {
        int k = ky * 7 + kx;
        float4 w4 = *(const float4*)&wvs[(g * 49 + k) * 32 + w_ * 4];
        acc0 = fmaf(w4.x, xw[0][kx], acc0);
        acc1 = fmaf(w4.y, xw[1][kx], acc1);
        acc2 = fmaf(w4.z, xw[2][kx], acc2);
        acc3 = fmaf(w4.w, xw[3][kx], acc3);
      }
    }
  }
  __syncthreads();                     // xs reads done; safe to alias with ob

  // ---- Phase E: transpose via LDS, coalesced store (+outer ReLU)
  {
    int c = ln;
    ob[c * 33 + 0 * 8 + w_] = fmaxf(acc0, 0.f);
    ob[c * 33 + 1 * 8 + w_] = fmaxf(acc1, 0.f);
    ob[c * 33 + 2 * 8 + w_] = fmaxf(acc2, 0.f);
    ob[c * 33 + 3 * 8 + w_] = fmaxf(acc3, 0.f);
  }
  __syncthreads();
  for (int j = tid; j < 2048; j += 512) {
    int c2 = j >> 5, pp = j & 31;
    int pr = pp >> 3, pc2 = pp & 7;
    int gy = oy0 + pr, gx = ox0 + pc2;
    if (gy < IH && gx < IW)
      y[c2 * HW + gy * IW + gx] = ob[c2 * 33 + pp];
  }
}

// ---------------------------------------------------------------- conv_out prep
__global__ __launch_bounds__(256) void transpose_w_kernel(
    const float* __restrict__ w, float* __restrict__ wt)
{
  int i = blockIdx.x * 256 + threadIdx.x;
  if (i >= 128 * 64 * 9) return;
  int oc = i / 576;
  int rem = i - oc * 576;
  int ci = rem / 9;
  int k = rem - ci * 9;
  wt[(k * 64 + ci) * 128 + oc] = w[i];
}

// ---------------------------------------------------------------- conv_out v4
// 8x8 tile, 4 waves x 16 oc = 64 oc/block, 2 oc-groups -> 512 blocks (2/CU).
// Each s_load weight batch (64 floats) and each ds_read_b128 of x now feeds
// 64 FMAs (v3: 32) -> scalar-fetch latency chains amortized 2x, LDS reads/CU
// halved (1152 vs 2304: ~9.6 us < 15.4 us FMA floor even at conflicted rate).
// xsm rows padded 10->16 px so each 8-lane octet read is one aligned 128B row
// (row stride 256B): <=2 rows/bank per quarter-wave -> bank-conflict-free.
__global__ __launch_bounds__(256, 2) void conv_out_kernel(
    const float* __restrict__ x, const float* __restrict__ wt,
    const float* __restrict__ b, float* __restrict__ y)
{
  __shared__ __align__(16) float xsm[16 * 160 * 4];   // 40,960 B
  int tid = threadIdx.x;
  int bx = blockIdx.x & 15, by = blockIdx.x >> 4;
  int oy0 = by * 8, ox0 = bx * 8;

  // stage 16 cq x 10 rows x 10 cols (row stride padded to 16 pixels)
  for (int u = tid; u < 1600; u += 256) {
    int cq = u / 100;
    int pos = u - cq * 100;
    int r = pos / 10;
    int c = pos - r * 10;
    int gy = oy0 + r, gx = ox0 + c;
    float4 v = make_float4(0.f, 0.f, 0.f, 0.f);
    if (gy < IH && gx < IW) {
      const float* xp = x + cq * 4 * HW + gy * IW + gx;
      v.x = xp[0]; v.y = xp[HW]; v.z = xp[2 * HW]; v.w = xp[3 * HW];
    }
    *(float4*)&xsm[(cq * 160 + r * 16 + c) * 4] = v;
  }
  __syncthreads();

  int ln = tid & 63;
  int px = ln & 7, py = ln >> 3;
  int wv_ = __builtin_amdgcn_readfirstlane(tid >> 6);   // wave 0..3
  int oc16 = blockIdx.y * 64 + wv_ * 16;

  float acc[16];
#pragma unroll
  for (int j = 0; j < 16; j++) acc[j] = b[oc16 + j];

#pragma unroll
  for (int ky = 0; ky < 3; ky++) {
#pragma unroll
    for (int kx = 0; kx < 3; kx++) {
      int k = ky * 3 + kx;
      const float* wp = wt + k * 64 * 128 + oc16;       // uniform -> s_loads
      const float* xbase = &xsm[((py + ky) * 16 + px + kx) * 4];
#pragma unroll 2
      for (int cq = 0; cq < 16; cq++) {
        float4 xv = *(const float4*)(xbase + cq * 640);
        const float* wq = wp + cq * 4 * 128;
#pragma unroll
        for (int j = 0; j < 16; j++) {
          acc[j] = fmaf(xv.x, wq[0 * 128 + j], acc[j]);
          acc[j] = fmaf(xv.y, wq[1 * 128 + j], acc[j]);
          acc[j] = fmaf(xv.z, wq[2 * 128 + j], acc[j]);
          acc[j] = fmaf(xv.w, wq[3 * 128 + j], acc[j]);
        }
      }
    }
  }

  int oy = oy0 + py, ox = ox0 + px;
  if (oy < OH && ox < OW) {
#pragma unroll
    for (int j = 0; j < 16; j++)
      y[(oc16 + j) * OHW + oy * OW + ox] = acc[j];
  }
}

// ---------------------------------------------------------------- launch
extern "C" void kernel_launch(void* const* d_in, const int* in_sizes, int n_in,
                              void* d_out, int out_size, void* d_ws, size_t ws_size,
                              hipStream_t stream)
{
  const float* input = (const float*)d_in[0];
  const float* ciw   = (const float*)d_in[1];
  const float* cib   = (const float*)d_in[2];
  const float* wred  = (const float*)d_in[3];
  const float* bred  = (const float*)d_in[4];
  const float* gam   = (const float*)d_in[5];
  const float* bet   = (const float*)d_in[6];
  const float* mu    = (const float*)d_in[7];
  const float* var   = (const float*)d_in[8];
  const float* wspan = (const float*)d_in[9];
  const float* bspan = (const float*)d_in[10];
  const float* cow   = (const float*)d_in[11];
  const float* cob   = (const float*)d_in[12];
  float* out = (float*)d_out;

  float* bufA = (float*)d_ws;                 // 64*126*126 = 1,016,064 floats
  float* bufB = bufA + (1 << 20);             // @ 4 MiB
  float* wt   = bufA + (1 << 21);             // @ 8 MiB, 73,728 floats

  transpose_w_kernel<<<288, 256, 0, stream>>>(cow, wt);
  conv_in_kernel<<<dim3(63, 64), 256, 0, stream>>>(input, ciw, cib, bufA);

  float* cur = bufA; float* nxt = bufB;
  for (int i = 0; i < 6; i++) {
    inv_kernel<<<512, 512, 0, stream>>>(cur, nxt,
        wred + i * 16 * 64, bred + i * 16, gam + i * 16, bet + i * 16,
        mu + i * 16, var + i * 16, wspan + i * 196 * 16, bspan + i * 196);
    float* t = cur; cur = nxt; nxt = t;
  }
  conv_out_kernel<<<dim3(256, 2), 256, 0, stream>>>(cur, wt, cob, out);
}

// Round 2
// 262.357 us; speedup vs baseline: 1.0031x; 1.0031x over previous
//
#include <hip/hip_runtime.h>

#define IH 126
#define IW 126
#define HW 15876      // 126*126
#define OH 124
#define OW 124
#define OHW 15376     // 124*124

// ---------------------------------------------------------------- conv_in
__global__ __launch_bounds__(256) void conv_in_kernel(
    const float* __restrict__ x, const float* __restrict__ w,
    const float* __restrict__ b, float* __restrict__ y)
{
  int pix = blockIdx.x * 256 + threadIdx.x;
  if (pix >= HW) return;
  int oc = blockIdx.y;                 // wave-uniform -> weights become s_loads
  int h  = pix / IW;
  int wc = pix - h * IW;
  const float* wp = w + oc * 27;
  float acc = b[oc];
#pragma unroll
  for (int ci = 0; ci < 3; ci++)
#pragma unroll
    for (int ky = 0; ky < 3; ky++)
#pragma unroll
      for (int kx = 0; kx < 3; kx++)
        acc = fmaf(x[ci * 128 * 128 + (h + ky) * 128 + (wc + kx)],
                   wp[ci * 9 + ky * 3 + kx], acc);
  y[oc * HW + pix] = acc;
}

// ---------------------------------------------------------------- involution v4
// Tile 8x4, 512 blocks (2/CU), 512 threads. ALL weight reads wave-uniform
// (s_load from scalar cache) — no per-thread vector global loads.
__global__ __launch_bounds__(512, 4) void inv_kernel(
    const float* __restrict__ x, float* __restrict__ y,
    const float* __restrict__ wr, const float* __restrict__ br,
    const float* __restrict__ gam, const float* __restrict__ bet,
    const float* __restrict__ mu, const float* __restrict__ var,
    const float* __restrict__ wspan, const float* __restrict__ bspan)
{
  __shared__ __align__(16) float xs[140][68];   // 38,080 B; aliased by ob[64][33] in E
  __shared__ __align__(16) float wvs[6272];     // 25,088 B; 196 pairs x 32 pixels
  __shared__ __align__(16) float tss[640];      // 2,560 B;  [32 pixels][20]
  float* ob  = &xs[0][0];                       // [64][33] alias

  int tid = threadIdx.x;
  int bx = blockIdx.x & 15, by = blockIdx.x >> 4;
  int ox0 = bx * 8, oy0 = by * 4;
  int xh0 = ox0 - 3, yh0 = oy0 - 3;

  // ---- Phase A: stage x halo (14 cols x 10 rows x 64 ch), zero-padded
  for (int idx = tid; idx < 140 * 64; idx += 512) {
    int c = idx / 140;
    int pos = idx - c * 140;
    int row = pos / 14;
    int col = pos - row * 14;
    int gy = yh0 + row, gx = xh0 + col;
    float v = 0.f;
    if (gy >= 0 && gy < IH && gx >= 0 && gx < IW)
      v = x[c * HW + gy * IW + gx];
    xs[pos][c] = v;
  }
  __syncthreads();

  int w_ = __builtin_amdgcn_readfirstlane(tid >> 6);  // wave 0..7
  int ln = tid & 63;
  int p  = ln & 31;                   // pixel 0..31 (upper 32 lanes duplicate)
  int prow = p >> 3, pcol = p & 7;
  int pc = (prow + 3) * 14 + (pcol + 3);

  // ---- Phase B: t = ReLU(BN(Wr.x)); wave w_ does cr = 2w_, 2w_+1 (uniform)
  {
    int cr0 = 2 * w_;
    const float* wa = wr + cr0 * 64;  // uniform -> s_load
    const float* wb = wa + 64;
    float a0 = 0.f, a1 = 0.f;
#pragma unroll
    for (int ci = 0; ci < 64; ci += 4) {
      float4 xv = *(const float4*)&xs[pc][ci];
      a0 = fmaf(xv.x, wa[ci + 0], a0); a1 = fmaf(xv.x, wb[ci + 0], a1);
      a0 = fmaf(xv.y, wa[ci + 1], a0); a1 = fmaf(xv.y, wb[ci + 1], a1);
      a0 = fmaf(xv.z, wa[ci + 2], a0); a1 = fmaf(xv.z, wb[ci + 2], a1);
      a0 = fmaf(xv.w, wa[ci + 3], a0); a1 = fmaf(xv.w, wb[ci + 3], a1);
    }
    float s0 = gam[cr0]     * rsqrtf(var[cr0]     + 1e-5f);
    float s1 = gam[cr0 + 1] * rsqrtf(var[cr0 + 1] + 1e-5f);
    float t0 = (a0 + br[cr0]     - mu[cr0])     * s0 + bet[cr0];
    float t1 = (a1 + br[cr0 + 1] - mu[cr0 + 1]) * s1 + bet[cr0 + 1];
    if (ln < 32) {
      tss[p * 20 + cr0]     = fmaxf(t0, 0.f);
      tss[p * 20 + cr0 + 1] = fmaxf(t1, 0.f);
    }
  }
  __syncthreads();

  // ---- Phase C: span. wave w_ owns uniform pairs (g*49+k) = w_ + 8j.
  {
    float tv[16];
#pragma unroll
    for (int i = 0; i < 4; i++) {
      float4 t4 = *(const float4*)&tss[p * 20 + 4 * i];
      tv[4 * i] = t4.x; tv[4 * i + 1] = t4.y;
      tv[4 * i + 2] = t4.z; tv[4 * i + 3] = t4.w;
    }
    for (int j = 0; j < 25; j++) {
      int pair = w_ + 8 * j;           // wave-uniform
      if (pair < 196) {
        const float* wk = wspan + pair * 16;   // uniform -> s_load_dwordx16
        float a = bspan[pair];
#pragma unroll
        for (int i = 0; i < 16; i++) a = fmaf(tv[i], wk[i], a);
        if (ln < 32) wvs[pair * 32 + pcol * 4 + prow] = a;
      }
    }
  }
  __syncthreads();

  // ---- Phase D: einsum. wave = output column w_, lane = channel.
  float acc0 = 0.f, acc1 = 0.f, acc2 = 0.f, acc3 = 0.f;
  {
    int c = ln;
    int g = ln >> 4;
    float xw[4][7];
#pragma unroll
    for (int r = 0; r < 4; r++)
#pragma unroll
      for (int kx = 0; kx < 7; kx++)
        xw[r][kx] = xs[r * 14 + w_ + kx][c];   // uniform base + lane: conflict-free
#pragma unroll
    for (int ky = 0; ky < 7; ky++) {
      if (ky > 0) {
#pragma unroll
        for (int r = 0; r < 3; r++)
#pragma unroll
          for (int kx = 0; kx < 7; kx++) xw[r][kx] = xw[r + 1][kx];
#pragma unroll
        for (int kx = 0; kx < 7; kx++)
          xw[3][kx] = xs[(ky + 3) * 14 + w_ + kx][c];
      }
#pragma unroll
      for (int kx = 0; kx < 7; kx++) {
        int k = ky * 7 + kx;
        float4 w4 = *(const float4*)&wvs[(g * 49 + k) * 32 + w_ * 4];
        acc0 = fmaf(w4.x, xw[0][kx], acc0);
        acc1 = fmaf(w4.y, xw[1][kx], acc1);
        acc2 = fmaf(w4.z, xw[2][kx], acc2);
        acc3 = fmaf(w4.w, xw[3][kx], acc3);
      }
    }
  }
  __syncthreads();                     // xs reads done; safe to alias with ob

  // ---- Phase E: transpose via LDS, coalesced store (+outer ReLU)
  {
    int c = ln;
    ob[c * 33 + 0 * 8 + w_] = fmaxf(acc0, 0.f);
    ob[c * 33 + 1 * 8 + w_] = fmaxf(acc1, 0.f);
    ob[c * 33 + 2 * 8 + w_] = fmaxf(acc2, 0.f);
    ob[c * 33 + 3 * 8 + w_] = fmaxf(acc3, 0.f);
  }
  __syncthreads();
  for (int j = tid; j < 2048; j += 512) {
    int c2 = j >> 5, pp = j & 31;
    int pr = pp >> 3, pc2 = pp & 7;
    int gy = oy0 + pr, gx = ox0 + pc2;
    if (gy < IH && gx < IW)
      y[c2 * HW + gy * IW + gx] = ob[c2 * 33 + pp];
  }
}

// ---------------------------------------------------------------- conv_out prep
// wt2 layout: [k][cq(16)][ocgrp(8)][ci4(4)][j(16)] — per (k,cq,ocgrp) the 64
// weight floats a wave needs are CONTIGUOUS -> one s_load_dwordx16 x4 batch.
__global__ __launch_bounds__(256) void transpose_w_kernel(
    const float* __restrict__ w, float* __restrict__ wt)
{
  int i = blockIdx.x * 256 + threadIdx.x;
  if (i >= 128 * 64 * 9) return;
  int oc = i / 576;
  int rem = i - oc * 576;
  int ci = rem / 9;
  int k = rem - ci * 9;
  int idx = ((k * 16 + (ci >> 2)) * 8 + (oc >> 4)) * 64 + (ci & 3) * 16 + (oc & 15);
  wt[idx] = w[i];
}

// ---------------------------------------------------------------- conv_out v5
// k-split across waves: 8x8 tile, 16 oc per BLOCK, waves split the 9 filter
// taps (wave w does k = w, w+4, w+8), LDS cross-wave reduce at the end.
// Grid 256 tiles x 8 oc-groups = 2048 blocks; LDS 25.6 KB -> 6 blocks/CU
// = 24 waves/CU (3x v4) to hide the s_load weight-fetch latency chains that
// capped v4 at VALUBusy 31%. 16 oc/lane keeps LDS pipe (~9.6 us/CU incl.
// conflicts) under the 14.5 us FMA floor.
__global__ __launch_bounds__(256, 6) void conv_out_kernel(
    const float* __restrict__ x, const float* __restrict__ wt,
    const float* __restrict__ b, float* __restrict__ y)
{
  __shared__ __align__(16) float xsm[16 * 100 * 4];   // 25,600 B; reduce buf alias
  int tid = threadIdx.x;
  int bx = blockIdx.x & 15, by = blockIdx.x >> 4;
  int oy0 = by * 8, ox0 = bx * 8;

  // stage 16 cq x 10 rows x 10 cols
  for (int u = tid; u < 1600; u += 256) {
    int cq = u / 100;
    int pos = u - cq * 100;
    int r = pos / 10;
    int c = pos - r * 10;
    int gy = oy0 + r, gx = ox0 + c;
    float4 v = make_float4(0.f, 0.f, 0.f, 0.f);
    if (gy < IH && gx < IW) {
      const float* xp = x + cq * 4 * HW + gy * IW + gx;
      v.x = xp[0]; v.y = xp[HW]; v.z = xp[2 * HW]; v.w = xp[3 * HW];
    }
    *(float4*)&xsm[u * 4] = v;
  }
  __syncthreads();

  int ln = tid & 63;
  int px = ln & 7, py = ln >> 3;
  int wv_ = __builtin_amdgcn_readfirstlane(tid >> 6);   // wave 0..3
  int oc16 = blockIdx.y * 16;

  float acc[16];
#pragma unroll
  for (int j = 0; j < 16; j++) acc[j] = (wv_ == 0) ? b[oc16 + j] : 0.f;

  // wave wv_ handles taps k = wv_, wv_+4, wv_+8 (balance {3,2,2,2})
  for (int kk = wv_; kk < 9; kk += 4) {
    int ky = kk / 3, kx = kk - ky * 3;
    const float* wp = wt + ((kk * 16) * 8 + blockIdx.y) * 64;   // uniform
    const float* xbase = &xsm[((py + ky) * 10 + px + kx) * 4];
#pragma unroll 2
    for (int cq = 0; cq < 16; cq++) {
      float4 xv = *(const float4*)(xbase + cq * 400);
      const float* wq = wp + cq * 512;          // one contiguous 64-float batch
#pragma unroll
      for (int j = 0; j < 16; j++) {
        acc[j] = fmaf(xv.x, wq[j],      acc[j]);
        acc[j] = fmaf(xv.y, wq[16 + j], acc[j]);
        acc[j] = fmaf(xv.z, wq[32 + j], acc[j]);
        acc[j] = fmaf(xv.w, wq[48 + j], acc[j]);
      }
    }
  }

  // cross-wave reduce via LDS (reuse xsm; 3*64*16 floats = 12,288 B)
  __syncthreads();
  if (wv_ > 0) {
#pragma unroll
    for (int j4 = 0; j4 < 4; j4++) {
      float4 v = make_float4(acc[4 * j4], acc[4 * j4 + 1],
                             acc[4 * j4 + 2], acc[4 * j4 + 3]);
      *(float4*)&xsm[(((wv_ - 1) * 64 + ln) * 16 + 4 * j4)] = v;
    }
  }
  __syncthreads();
  if (wv_ == 0) {
#pragma unroll
    for (int j = 0; j < 16; j++)
      acc[j] += xsm[(0 * 64 + ln) * 16 + j]
              + xsm[(1 * 64 + ln) * 16 + j]
              + xsm[(2 * 64 + ln) * 16 + j];
    int oy = oy0 + py, ox = ox0 + px;
    if (oy < OH && ox < OW) {
#pragma unroll
      for (int j = 0; j < 16; j++)
        y[(oc16 + j) * OHW + oy * OW + ox] = acc[j];
    }
  }
}

// ---------------------------------------------------------------- launch
extern "C" void kernel_launch(void* const* d_in, const int* in_sizes, int n_in,
                              void* d_out, int out_size, void* d_ws, size_t ws_size,
                              hipStream_t stream)
{
  const float* input = (const float*)d_in[0];
  const float* ciw   = (const float*)d_in[1];
  const float* cib   = (const float*)d_in[2];
  const float* wred  = (const float*)d_in[3];
  const float* bred  = (const float*)d_in[4];
  const float* gam   = (const float*)d_in[5];
  const float* bet   = (const float*)d_in[6];
  const float* mu    = (const float*)d_in[7];
  const float* var   = (const float*)d_in[8];
  const float* wspan = (const float*)d_in[9];
  const float* bspan = (const float*)d_in[10];
  const float* cow   = (const float*)d_in[11];
  const float* cob   = (const float*)d_in[12];
  float* out = (float*)d_out;

  float* bufA = (float*)d_ws;                 // 64*126*126 = 1,016,064 floats
  float* bufB = bufA + (1 << 20);             // @ 4 MiB
  float* wt   = bufA + (1 << 21);             // @ 8 MiB, 73,728 floats

  transpose_w_kernel<<<288, 256, 0, stream>>>(cow, wt);
  conv_in_kernel<<<dim3(63, 64), 256, 0, stream>>>(input, ciw, cib, bufA);

  float* cur = bufA; float* nxt = bufB;
  for (int i = 0; i < 6; i++) {
    inv_kernel<<<512, 512, 0, stream>>>(cur, nxt,
        wred + i * 16 * 64, bred + i * 16, gam + i * 16, bet + i * 16,
        mu + i * 16, var + i * 16, wspan + i * 196 * 16, bspan + i * 196);
    float* t = cur; cur = nxt; nxt = t;
  }
  conv_out_kernel<<<dim3(256, 8), 256, 0, stream>>>(cur, wt, cob, out);
}